// Round 3
// baseline (264.399 us; speedup 1.0000x reference)
//
#include <hip/hip_runtime.h>
#include <hip/hip_cooperative_groups.h>
#include <math.h>

// NoiseGenerator R6: ONE cooperative dispatch, exact block-state decomposition.
//   out[n] = HP(LP(noise))[n] * env[n] * gain
//   State s=(y,z): s[n] = M s[n-1] + v x[n], M = [[a,0],[b(a-1),b]] (lower-tri,
//   operators are 3 floats, compose = 3 FMAs; powers of M commute).
//
// vs R5b (two dispatches, 80.5us): the split paid a second launch/graph gap
// AND a full 16.8MB re-read of noise in k2. Merge into one kernel with a
// grid-wide barrier (hipLaunchCooperativeKernel; grid=1024 = 4 blocks/CU x
// 256 CU co-resident at __launch_bounds__(256,4)):
//  - Phase 1: x -> registers (4x dwordx4, 64B lane stride), per-thread
//    zero-state chain writing z-responses IN PLACE into the x registers,
//    shfl scan for block-local prefix, block end-state E_b (8 B) -> d_ws.
//  - grid.sync(): registers (incl. the 16 z-responses) survive the barrier;
//    noise is read ONCE total.
//  - Phase 2: exact incoming state s0 = sum_{u<b} Q^{b-1-u} E_u (Q=M^4096)
//    via per-thread Horner over <=4 E entries + Q^tid weighting + 256-thread
//    reduce; then per-sample total z = z_zerostate + (M^{j+1} T_t)_z is a
//    3-FMA homogeneous chain (linearity; no x needed); envelope; store from
//    registers.
//  - Fallback: if cooperative launch is rejected, run the proven R5b
//    two-kernel path (identical math).
// Traffic: 16.78MB read + 16.78MB write + 16KB states ~ 5.5us roofline.

#define BLOCK 256
#define CHUNK 16
#define SAMP  (BLOCK * CHUNK)   // 4096 samples per block -> grid 1024 @ n=2^22
#define ESTG_CAP 4096           // fallback scratch: supports grid <= 2048

typedef float vfloat4 __attribute__((ext_vector_type(4)));
typedef float vfloat2 __attribute__((ext_vector_type(2)));

namespace cg = cooperative_groups;

__device__ float Est_g[ESTG_CAP];   // loader-allocated fallback scratch

struct Op { float a, w, b; };   // [[a,0],[w,b]]
__device__ __forceinline__ Op opmul(Op A, Op B) {   // A*B
    Op C;
    C.a = A.a * B.a;
    C.w = fmaf(A.w, B.a, A.b * B.w);
    C.b = A.b * B.b;
    return C;
}

// ---------------------------------------------------------------------------
// R6 cooperative single-dispatch kernel
// ---------------------------------------------------------------------------
__global__ __launch_bounds__(BLOCK, 4) void ng_coop(
    const float* __restrict__ params,
    const float* __restrict__ noise,
    float* __restrict__ out,
    float* __restrict__ EstArg,
    int n)
{
    __shared__ float swy[4], swz[4], ry[4], rz[4];
    float* __restrict__ Est = EstArg ? EstArg : Est_g;

    const int tid  = threadIdx.x;
    const int lane = tid & 63;
    const int wid  = tid >> 6;
    const int b    = blockIdx.x;
    const int g0   = b * SAMP + tid * CHUNK;

    const float a   = fminf(fmaxf(params[2], 1e-7f), 0.99f);
    const float bb  = fminf(fmaxf(params[3], 1e-7f), 0.99f);
    const float omc = 1.0f - a;

    // ---- per-thread x in registers: 4x float4, 64B lane stride ----
    vfloat4 xq[4];
    if (g0 + CHUNK <= n) {
        #pragma unroll
        for (int q = 0; q < 4; ++q)
            xq[q] = *(const vfloat4*)(noise + g0 + 4 * q);
    } else {
        #pragma unroll
        for (int q = 0; q < 4; ++q) {
            #pragma unroll
            for (int c = 0; c < 4; ++c) {
                int g = g0 + 4 * q + c;
                xq[q][c] = (g < n) ? noise[g] : 0.0f;
            }
        }
    }

    // ---- zero-state chain; write z-response IN PLACE into xq ----
    float yv = 0.0f, zv = 0.0f;
    #pragma unroll
    for (int j = 0; j < CHUNK; ++j) {
        float x  = xq[j >> 2][j & 3];
        float yn = fmaf(a, yv, omc * x);
        zv = bb * (zv + (yn - yv));
        yv = yn;
        xq[j >> 2][j & 3] = zv;     // own register slot
    }

    // ---- intra-wave Hillis-Steele scan (operator squaring) ----
    Op m1 = { a, bb * (a - 1.0f), bb };
    Op m2 = opmul(m1, m1), m4 = opmul(m2, m2), m8 = opmul(m4, m4);
    Op P  = opmul(m8, m8);          // M^16 = M^CHUNK
    Op O  = { 1.0f, 0.0f, 1.0f };   // M^(CHUNK*lane), built from pre-square P
    float cy = yv, cz = zv;
    #pragma unroll
    for (int k = 0; k < 6; ++k) {
        if ((lane >> k) & 1) O = opmul(P, O);
        int d = 1 << k;
        float py = __shfl_up(cy, d, 64);
        float pz = __shfl_up(cz, d, 64);
        if (lane >= d) {
            cy = fmaf(P.a, py, cy);
            cz = fmaf(P.w, py, fmaf(P.b, pz, cz));
        }
        P = opmul(P, P);            // after loop: P = R = M^1024 (wave op)
    }
    if (lane == 63) { swy[wid] = cy; swz[wid] = cz; }
    __syncthreads();                // barrier 1

    // cross-wave zero-init prefix: state entering this wave (block-local)
    float pry = 0.0f, prz = 0.0f;
    for (int u = 0; u < wid; ++u) { // wave-uniform trip count
        float ny = fmaf(P.a, pry, swy[u]);
        float nz = fmaf(P.w, pry, fmaf(P.b, prz, swz[u]));
        pry = ny; prz = nz;
    }

    // exclusive intra-wave zero-state value (before cy/cz die)
    float ey = __shfl_up(cy, 1, 64);
    float ez = __shfl_up(cz, 1, 64);
    if (lane == 0) { ey = 0.0f; ez = 0.0f; }

    // publish block end state E_b = R*pref_3 + S_3
    if (tid == 255) {
        vfloat2 e;
        e.x = fmaf(P.a, pry, cy);
        e.y = fmaf(P.w, pry, fmaf(P.b, prz, cz));
        *(vfloat2*)(Est + 2 * b) = e;
    }
    __threadfence();                // device-scope release of E_b
    cg::this_grid().sync();         // ---- grid barrier (regs survive) ----

    // ---- s0 = sum_{u<b} Q^{b-1-u} E_u,  Q = M^4096 ----
    int em = b - 1 - tid;
    int nt = (em >= 0) ? ((em >> 8) + 1) : 0;
    vfloat2 Ev[4] = {{0.f,0.f},{0.f,0.f},{0.f,0.f},{0.f,0.f}};
    #pragma unroll
    for (int j = 0; j < 4; ++j) {
        if (j < nt) {
            int u = b - 1 - tid - (j << 8);
            Ev[j] = *(const vfloat2*)(Est + 2 * u);
        }
    }
    Op R2 = opmul(P, P);            // M^2048
    Op Q  = opmul(R2, R2);          // M^4096
    Op Ot = { 1.0f, 0.0f, 1.0f };   // Q^tid
    Op cur = Q;
    #pragma unroll
    for (int k = 0; k < 8; ++k) {
        if ((tid >> k) & 1) Ot = opmul(cur, Ot);
        cur = opmul(cur, cur);      // after loop: cur = Q^256
    }
    float Hy = 0.0f, Hz = 0.0f;
    for (int j = nt - 1; j >= 4; --j) {          // general-n fallback (dead @ n=2^22)
        int u = b - 1 - tid - (j << 8);
        vfloat2 e = *(const vfloat2*)(Est + 2 * u);
        float t = fmaf(cur.a, Hy, e.x);
        Hz = fmaf(cur.w, Hy, fmaf(cur.b, Hz, e.y));
        Hy = t;
    }
    #pragma unroll
    for (int j = 3; j >= 0; --j) {
        if (j < nt) {
            float t = fmaf(cur.a, Hy, Ev[j].x);
            Hz = fmaf(cur.w, Hy, fmaf(cur.b, Hz, Ev[j].y));
            Hy = t;
        }
    }
    // weighted contribution Q^tid * H, then 256-thread sum-reduce
    float vy = Ot.a * Hy;
    float vz = fmaf(Ot.w, Hy, Ot.b * Hz);
    #pragma unroll
    for (int d = 1; d < 64; d <<= 1) {
        vy += __shfl_xor(vy, d, 64);
        vz += __shfl_xor(vz, d, 64);
    }
    if (lane == 0) { ry[wid] = vy; rz[wid] = vz; }
    __syncthreads();                // barrier 2
    float s0y = (ry[0] + ry[1]) + (ry[2] + ry[3]);
    float s0z = (rz[0] + rz[1]) + (rz[2] + rz[3]);

    // ---- thread incoming TRUE state T_t = O*(R^wid*s0 + pref_wid) + excl ----
    float wy = s0y, wz = s0z;
    for (int u = 0; u < wid; ++u) { // R^wid * s0, wave-uniform
        float t = P.a * wy;
        wz = fmaf(P.w, wy, P.b * wz);
        wy = t;
    }
    wy += pry; wz += prz;
    float yh = fmaf(O.a, wy, ey);
    float zh = ez + fmaf(O.w, wy, O.b * wz);

    // ---- homogeneous correction + envelope, in registers ----
    const float attack = fmaxf(params[0], 1e-7f);
    const float decay  = fmaxf(params[1], 1e-7f);
    const float gain   = fmaxf(params[4], 1e-7f);
    const float inv    = 1.0f / (float)(n - 1);
    const float ia = -1.0f / attack;
    const float id = -1.0f / decay;
    const float t0 = (float)g0 * inv;           // g0 >= 0: no overflow
    float ea = __expf(ia * t0);                 // exp(-t/attack) running product
    float ed = __expf(id * t0) * gain;          // exp(-t/decay) * gain
    const float ra = __expf(ia * inv);
    const float rd = __expf(id * inv);

    #pragma unroll
    for (int j = 0; j < CHUNK; ++j) {
        float yn = a * yh;                      // h_{j} = M h_{j-1}, h_{-1}=T_t
        zh = bb * (zh + (yn - yh));
        yh = yn;
        float zt = xq[j >> 2][j & 3] + zh;      // total = zero-state + homog
        xq[j >> 2][j & 3] = zt * ((1.0f - ea) * ed);
        ea *= ra; ed *= rd;
    }
    if (g0 + CHUNK <= n) {
        #pragma unroll
        for (int q = 0; q < 4; ++q)
            *(vfloat4*)(out + g0 + 4 * q) = xq[q];
    } else {
        #pragma unroll
        for (int q = 0; q < 4; ++q) {
            #pragma unroll
            for (int c = 0; c < 4; ++c) {
                int g = g0 + 4 * q + c;
                if (g < n) out[g] = xq[q][c];
            }
        }
    }
}

// ---------------------------------------------------------------------------
// R5b two-kernel fallback (identical math), used only if the cooperative
// launch is rejected by the runtime/graph capture.
// ---------------------------------------------------------------------------
template<bool EMIT>
__global__ __launch_bounds__(BLOCK, 4) void ng_kernel(
    const float* __restrict__ params,
    const float* __restrict__ noise,
    float* __restrict__ out,
    float* __restrict__ EstArg,
    int n)
{
    __shared__ float swy[4], swz[4], ry[4], rz[4];
    float* __restrict__ Est = EstArg ? EstArg : Est_g;

    const int tid  = threadIdx.x;
    const int lane = tid & 63;
    const int wid  = tid >> 6;
    const int b    = blockIdx.x;
    const int g0   = b * SAMP + tid * CHUNK;

    const float a   = fminf(fmaxf(params[2], 1e-7f), 0.99f);
    const float bb  = fminf(fmaxf(params[3], 1e-7f), 0.99f);
    const float omc = 1.0f - a;

    int nt = 0;
    vfloat2 Ev[4] = {{0.f,0.f},{0.f,0.f},{0.f,0.f},{0.f,0.f}};
    if (EMIT) {
        int em = b - 1 - tid;
        nt = (em >= 0) ? ((em >> 8) + 1) : 0;
        #pragma unroll
        for (int j = 0; j < 4; ++j) {
            if (j < nt) {
                int u = b - 1 - tid - (j << 8);
                Ev[j] = *(const vfloat2*)(Est + 2 * u);
            }
        }
    }

    vfloat4 xq[4];
    if (g0 + CHUNK <= n) {
        #pragma unroll
        for (int q = 0; q < 4; ++q)
            xq[q] = *(const vfloat4*)(noise + g0 + 4 * q);
    } else {
        #pragma unroll
        for (int q = 0; q < 4; ++q) {
            #pragma unroll
            for (int c = 0; c < 4; ++c) {
                int g = g0 + 4 * q + c;
                xq[q][c] = (g < n) ? noise[g] : 0.0f;
            }
        }
    }

    float yv = 0.0f, zv = 0.0f;
    #pragma unroll
    for (int j = 0; j < CHUNK; ++j) {
        float x  = xq[j >> 2][j & 3];
        float yn = fmaf(a, yv, omc * x);
        zv = bb * (zv + (yn - yv));
        yv = yn;
    }

    Op m1 = { a, bb * (a - 1.0f), bb };
    Op m2 = opmul(m1, m1), m4 = opmul(m2, m2), m8 = opmul(m4, m4);
    Op P  = opmul(m8, m8);
    Op O  = { 1.0f, 0.0f, 1.0f };
    float cy = yv, cz = zv;
    #pragma unroll
    for (int k = 0; k < 6; ++k) {
        if (EMIT && ((lane >> k) & 1)) O = opmul(P, O);
        int d = 1 << k;
        float py = __shfl_up(cy, d, 64);
        float pz = __shfl_up(cz, d, 64);
        if (lane >= d) {
            cy = fmaf(P.a, py, cy);
            cz = fmaf(P.w, py, fmaf(P.b, pz, cz));
        }
        P = opmul(P, P);
    }
    if (lane == 63) { swy[wid] = cy; swz[wid] = cz; }
    __syncthreads();

    float pry = 0.0f, prz = 0.0f;
    for (int u = 0; u < wid; ++u) {
        float ny = fmaf(P.a, pry, swy[u]);
        float nz = fmaf(P.w, pry, fmaf(P.b, prz, swz[u]));
        pry = ny; prz = nz;
    }

    if (!EMIT) {
        if (tid == 255) {
            vfloat2 e;
            e.x = fmaf(P.a, pry, cy);
            e.y = fmaf(P.w, pry, fmaf(P.b, prz, cz));
            *(vfloat2*)(Est + 2 * b) = e;
        }
        return;
    }

    float ey = __shfl_up(cy, 1, 64);
    float ez = __shfl_up(cz, 1, 64);
    if (lane == 0) { ey = 0.0f; ez = 0.0f; }

    Op R2 = opmul(P, P);
    Op Q  = opmul(R2, R2);
    Op Ot = { 1.0f, 0.0f, 1.0f };
    Op cur = Q;
    #pragma unroll
    for (int k = 0; k < 8; ++k) {
        if ((tid >> k) & 1) Ot = opmul(cur, Ot);
        cur = opmul(cur, cur);
    }
    float Hy = 0.0f, Hz = 0.0f;
    for (int j = nt - 1; j >= 4; --j) {
        int u = b - 1 - tid - (j << 8);
        vfloat2 e = *(const vfloat2*)(Est + 2 * u);
        float t = fmaf(cur.a, Hy, e.x);
        Hz = fmaf(cur.w, Hy, fmaf(cur.b, Hz, e.y));
        Hy = t;
    }
    #pragma unroll
    for (int j = 3; j >= 0; --j) {
        if (j < nt) {
            float t = fmaf(cur.a, Hy, Ev[j].x);
            Hz = fmaf(cur.w, Hy, fmaf(cur.b, Hz, Ev[j].y));
            Hy = t;
        }
    }
    float vy = Ot.a * Hy;
    float vz = fmaf(Ot.w, Hy, Ot.b * Hz);
    #pragma unroll
    for (int d = 1; d < 64; d <<= 1) {
        vy += __shfl_xor(vy, d, 64);
        vz += __shfl_xor(vz, d, 64);
    }
    if (lane == 0) { ry[wid] = vy; rz[wid] = vz; }
    __syncthreads();
    float s0y = (ry[0] + ry[1]) + (ry[2] + ry[3]);
    float s0z = (rz[0] + rz[1]) + (rz[2] + rz[3]);

    float wy = s0y, wz = s0z;
    for (int u = 0; u < wid; ++u) {
        float t = P.a * wy;
        wz = fmaf(P.w, wy, P.b * wz);
        wy = t;
    }
    wy += pry; wz += prz;
    float y0 = fmaf(O.a, wy, ey);
    float z0 = ez + fmaf(O.w, wy, O.b * wz);

    const float attack = fmaxf(params[0], 1e-7f);
    const float decay  = fmaxf(params[1], 1e-7f);
    const float gain   = fmaxf(params[4], 1e-7f);
    const float inv    = 1.0f / (float)(n - 1);
    const float ia = -1.0f / attack;
    const float id = -1.0f / decay;
    const float t0 = (float)g0 * inv;
    float ea = __expf(ia * t0);
    float ed = __expf(id * t0) * gain;
    const float ra = __expf(ia * inv);
    const float rd = __expf(id * inv);

    vfloat4 oq[4];
    yv = y0; zv = z0;
    #pragma unroll
    for (int j = 0; j < CHUNK; ++j) {
        float x  = xq[j >> 2][j & 3];
        float yn = fmaf(a, yv, omc * x);
        zv = bb * (zv + (yn - yv));
        yv = yn;
        oq[j >> 2][j & 3] = zv * ((1.0f - ea) * ed);
        ea *= ra; ed *= rd;
    }
    if (g0 + CHUNK <= n) {
        #pragma unroll
        for (int q = 0; q < 4; ++q)
            *(vfloat4*)(out + g0 + 4 * q) = oq[q];
    } else {
        #pragma unroll
        for (int q = 0; q < 4; ++q) {
            #pragma unroll
            for (int c = 0; c < 4; ++c) {
                int g = g0 + 4 * q + c;
                if (g < n) out[g] = oq[q][c];
            }
        }
    }
}

extern "C" void kernel_launch(void* const* d_in, const int* in_sizes, int n_in,
                              void* d_out, int out_size, void* d_ws, size_t ws_size,
                              hipStream_t stream) {
    const float* params = (const float*)d_in[0];
    const float* noise  = (const float*)d_in[1];
    float* out = (float*)d_out;
    int n = in_sizes[1];
    int grid = (n + SAMP - 1) / SAMP;   // 1024 blocks @ n = 4194304
    float* Est = (ws_size >= (size_t)(2 * grid) * sizeof(float))
                     ? (float*)d_ws : nullptr;   // nullptr -> Est_g in-kernel

    void* args[] = { (void*)&params, (void*)&noise, (void*)&out,
                     (void*)&Est, (void*)&n };
    hipError_t err = hipLaunchCooperativeKernel(
        reinterpret_cast<void*>(ng_coop), dim3(grid), dim3(BLOCK),
        args, 0, stream);
    if (err != hipSuccess) {
        // graph-capture or occupancy rejection: proven two-kernel path
        ng_kernel<false><<<grid, BLOCK, 0, stream>>>(params, noise, out, Est, n);
        ng_kernel<true ><<<grid, BLOCK, 0, stream>>>(params, noise, out, Est, n);
    }
}

// Round 4
// 84.824 us; speedup vs baseline: 3.1170x; 3.1170x over previous
//
#include <hip/hip_runtime.h>
#include <math.h>

// NoiseGenerator R7: ONE plain dispatch, register-resident, halo-truncated.
//   out[n] = HP(LP(noise))[n] * env[n] * gain
//   State s=(y,z): s[n] = M s[n-1] + v x[n], M = [[a,0],[b(a-1),b]] (lower-tri;
//   operators are 3 floats, compose = 3 FMAs; powers of M commute).
//
// Lessons: R6 proved cg::this_grid().sync() costs ~170us on gfx950 (ng_coop
// 185us @ VALUBusy 2.4%); R5b proved a second dependent dispatch costs ~12us
// in node overhead + a full re-read. So: single dispatch, zero cross-block
// communication, block-local truncated recurrence (R4b's proven halo trick:
// c<=0.99 -> 0.99^1280 ~ 2.6e-6 decay; R4b passed with identical absmax
// 1.525879e-05 = fp32 rounding floor -- truncation invisible).
//
// vs R4b (LDS staging, 3 barriers, ~23-30us kernel):
//  - Register data path: thread t loads its 20 samples directly as 5 aligned
//    float4 (lane stride 80B; wave covers a dense 5KB window; L1 merges, each
//    line fetched once, halo re-reads L3-hit). No 21.5KB LDS stage, no
//    scalar LDS round trips.
//  - CHUNK=20, HALO=1280=64*20: wave 0 is EXACTLY the halo -> writer threads
//    (waves 1-3) all start at g>=0: the exp-overflow guard and per-sample
//    li>=HALO checks vanish; stores are 5 aligned float4 per thread.
//  - Barriers 3 -> 1 (one 32B LDS exchange of wave end-states).
//  - Phase B writes zero-state z into own registers; phase D adds the
//    homogeneous correction (M^{j+1} s_in)_z and the envelope in registers.
// Traffic: 1093 blocks * 20KB read + 16.8MB write ~ 39MB ~ 6.5us roofline.

#define BLOCK 256
#define CHUNK 20
#define HALO  1280                  // 64 threads * CHUNK = wave 0 exactly
#define TWORDS (BLOCK * CHUNK)      // 5120 samples spanned per block
#define SAMP   (TWORDS - HALO)      // 3840 output samples per block

typedef float vfloat4 __attribute__((ext_vector_type(4)));

struct Op { float a, w, b; };       // [[a,0],[w,b]]
__device__ __forceinline__ Op opmul(Op A, Op B) {   // A*B
    Op C;
    C.a = A.a * B.a;
    C.w = fmaf(A.w, B.a, A.b * B.w);
    C.b = A.b * B.b;
    return C;
}

__global__ __launch_bounds__(BLOCK) void ng_halo(
    const float* __restrict__ params,
    const float* __restrict__ noise,
    float* __restrict__ out, int n)
{
    __shared__ float swy[4], swz[4];

    const int tid  = threadIdx.x;
    const int lane = tid & 63;
    const int wid  = tid >> 6;
    const int base = blockIdx.x * SAMP - HALO;  // <0 only for block 0
    const int g0   = base + tid * CHUNK;

    const float a   = fminf(fmaxf(params[2], 1e-7f), 0.99f);
    const float bb  = fminf(fmaxf(params[3], 1e-7f), 0.99f);
    const float omc = 1.0f - a;

    // ---- per-thread x in registers: 5 aligned float4, 80B lane stride ----
    vfloat4 xq[5];
    if (g0 >= 0 && g0 + CHUNK <= n) {
        #pragma unroll
        for (int q = 0; q < 5; ++q)
            xq[q] = *(const vfloat4*)(noise + g0 + 4 * q);
    } else {                                    // block 0 halo & last block tail
        #pragma unroll
        for (int q = 0; q < 5; ++q) {
            #pragma unroll
            for (int c = 0; c < 4; ++c) {
                int g = g0 + 4 * q + c;
                xq[q][c] = (g >= 0 && g < n) ? noise[g] : 0.0f;
            }
        }
    }

    // ---- phase B: zero-state chain; write z-response in place (regs) ----
    float yv = 0.0f, zv = 0.0f;
    #pragma unroll
    for (int j = 0; j < CHUNK; ++j) {
        float x  = xq[j >> 2][j & 3];
        float yn = fmaf(a, yv, omc * x);
        zv = bb * (zv + (yn - yv));
        yv = yn;
        xq[j >> 2][j & 3] = zv;                 // own register slot
    }

    // ---- intra-wave Hillis-Steele scan (operator squaring) ----
    Op m1 = { a, bb * (a - 1.0f), bb };
    Op m2 = opmul(m1, m1), m4 = opmul(m2, m2), m8 = opmul(m4, m4), m16 = opmul(m8, m8);
    Op P  = opmul(m16, m4);         // M^20 = M^CHUNK
    Op O  = { 1.0f, 0.0f, 1.0f };   // M^(CHUNK*lane), built from pre-square P
    float cy = yv, cz = zv;
    #pragma unroll
    for (int k = 0; k < 6; ++k) {
        if ((lane >> k) & 1) O = opmul(P, O);
        int d = 1 << k;
        float py = __shfl_up(cy, d, 64);
        float pz = __shfl_up(cz, d, 64);
        if (lane >= d) {
            cy = fmaf(P.a, py, cy);
            cz = fmaf(P.w, py, fmaf(P.b, pz, cz));
        }
        P = opmul(P, P);            // after loop: P = M^1280 (wave operator)
    }
    if (lane == 63) { swy[wid] = cy; swz[wid] = cz; }

    // exclusive intra-wave zero-state value
    float ey = __shfl_up(cy, 1, 64);
    float ez = __shfl_up(cz, 1, 64);
    if (lane == 0) { ey = 0.0f; ez = 0.0f; }

    __syncthreads();                // the only barrier

    // wave 0 == halo exactly: prefix-only, no output
    if (tid < HALO / CHUNK) return;

    // cross-wave zero-init prefix: state entering this wave (block-local)
    float pry = 0.0f, prz = 0.0f;
    for (int u = 0; u < wid; ++u) { // wave-uniform trip count (wid>=1 here)
        float ny = fmaf(P.a, pry, swy[u]);
        float nz = fmaf(P.w, pry, fmaf(P.b, prz, swz[u]));
        pry = ny; prz = nz;
    }

    // thread incoming state s_in = O * pref_wid + excl  (block-zero-state)
    float yh = fmaf(O.a, pry, ey);
    float zh = ez + fmaf(O.w, pry, O.b * prz);

    // ---- phase D: homogeneous correction + envelope, in registers ----
    // all writer threads have g0 >= 0 (g0 >= block output start)
    const float attack = fmaxf(params[0], 1e-7f);
    const float decay  = fmaxf(params[1], 1e-7f);
    const float gain   = fmaxf(params[4], 1e-7f);
    const float inv    = 1.0f / (float)(n - 1);
    const float ia = -1.0f / attack;
    const float id = -1.0f / decay;
    const float t0 = (float)g0 * inv;           // >= 0: no overflow case
    float ea = __expf(ia * t0);                 // exp(-t/attack) running product
    float ed = __expf(id * t0) * gain;          // exp(-t/decay) * gain
    const float ra = __expf(ia * inv);
    const float rd = __expf(id * inv);

    #pragma unroll
    for (int j = 0; j < CHUNK; ++j) {
        float yn = a * yh;                      // h_j = M h_{j-1}, h_{-1} = s_in
        zh = bb * (zh + (yn - yh));
        yh = yn;
        float zt = xq[j >> 2][j & 3] + zh;      // total = zero-state + homog
        xq[j >> 2][j & 3] = zt * ((1.0f - ea) * ed);
        ea *= ra; ed *= rd;
    }

    // ---- 5 aligned nontemporal float4 stores from registers ----
    if (g0 + CHUNK <= n) {
        #pragma unroll
        for (int q = 0; q < 5; ++q)
            __builtin_nontemporal_store(xq[q], (vfloat4*)(out + g0 + 4 * q));
    } else {                                    // last block tail
        #pragma unroll
        for (int q = 0; q < 5; ++q) {
            #pragma unroll
            for (int c = 0; c < 4; ++c) {
                int g = g0 + 4 * q + c;
                if (g < n) out[g] = xq[q][c];
            }
        }
    }
}

extern "C" void kernel_launch(void* const* d_in, const int* in_sizes, int n_in,
                              void* d_out, int out_size, void* d_ws, size_t ws_size,
                              hipStream_t stream) {
    const float* params = (const float*)d_in[0];
    const float* noise  = (const float*)d_in[1];
    float* out = (float*)d_out;
    int n = in_sizes[1];
    int grid = (n + SAMP - 1) / SAMP;   // 1093 blocks @ n = 4194304
    ng_halo<<<grid, BLOCK, 0, stream>>>(params, noise, out, n);
}

// Round 5
// 74.799 us; speedup vs baseline: 3.5348x; 1.1340x over previous
//
#include <hip/hip_runtime.h>
#include <math.h>

// NoiseGenerator R8: coalesced global <-> LDS transpose <-> register compute.
//   out[n] = HP(LP(noise))[n] * env[n] * gain
//   State s=(y,z): s[n] = M s[n-1] + v x[n], M = [[a,0],[b(a-1),b]] (lower-tri;
//   operators are 3 floats, compose = 3 FMAs; powers of M commute).
//
// Evidence so far: R4b (LDS-staged, coalesced, scalar middle) = 75.45us best;
// R7 (register-direct, 80B-stride global access) = 84.8us; R5b (2 dispatches)
// = 80.5us; R6 (grid.sync) = 264us. Coalescing dominates; LDS transposes are
// mandatory; the scalar-LDS middle of R4b is the only removable cost left.
//
// R8 = R4b's global pattern + R7's register middle:
//  - stage: coalesced float4 global->LDS (each 64B line fetched once).
//  - transpose out: each thread ds_read_b128 x5 = its contiguous 20 samples.
//    CHUNK=20 -> 5 16B-slots/thread, 5 odd -> slot group (5t+q) mod 8 is a
//    lane permutation -> conflict-minimal b128, no padding, 16B-aligned.
//  - middle (validated in R7): zero-state chain + shfl operator scan +
//    homogeneous correction + envelope, all in registers. No z write-back,
//    no LDS re-read, no per-sample guards.
//  - transpose back: ds_write_b128 x5 of outputs IN PLACE (own slots; only
//    the owner touches them between the two data barriers).
//  - store: coalesced nontemporal float4 from LDS (full-line writes).
//  - HALO=1280=64*CHUNK: wave 0 is exactly the halo (prefix-only, no store);
//    writer threads all have g0>=0 -> no exp-overflow case, env exact at t=0.
//    Truncation 0.99^1280 ~ 2.6e-6, invisible at the 1.53e-5 fp32 floor (R4b/R7).
//  - LDS 20.5KB -> ~6 blocks/CU (R4b: 4), scalar LDS ops 74 -> 0, b128 ~19.
// Traffic: 22.4MB read (incl halo, L2/L3-hot) + 16.8MB write ~ 6.5us roofline.

#define BLOCK 256
#define CHUNK 20
#define HALO  1280                  // 64 threads * CHUNK = wave 0 exactly
#define TWORDS (BLOCK * CHUNK)      // 5120 samples spanned per block (20 KB)
#define SAMP   (TWORDS - HALO)      // 3840 output samples per block

typedef float vfloat4 __attribute__((ext_vector_type(4)));

struct Op { float a, w, b; };       // [[a,0],[w,b]]
__device__ __forceinline__ Op opmul(Op A, Op B) {   // A*B
    Op C;
    C.a = A.a * B.a;
    C.w = fmaf(A.w, B.a, A.b * B.w);
    C.b = A.b * B.b;
    return C;
}

__global__ __launch_bounds__(BLOCK) void ng_r8(
    const float* __restrict__ params,
    const float* __restrict__ noise,
    float* __restrict__ out, int n)
{
    __shared__ __align__(16) float xs[TWORDS];
    __shared__ float swy[4], swz[4];

    const int tid  = threadIdx.x;
    const int lane = tid & 63;
    const int wid  = tid >> 6;
    const int B    = blockIdx.x * SAMP;
    const int base = B - HALO;                  // <0 only for block 0

    const float a   = fminf(fmaxf(params[2], 1e-7f), 0.99f);
    const float bb  = fminf(fmaxf(params[3], 1e-7f), 0.99f);
    const float omc = 1.0f - a;

    // ---- stage [base, base+TWORDS) into LDS, coalesced float4 ----
    for (int v = tid; v < (TWORDS >> 2); v += BLOCK) {
        int i = v << 2;
        int g = base + i;
        vfloat4 val;
        if (g >= 0 && g + 4 <= n) {
            val = *(const vfloat4*)(noise + g);
        } else {                                // block 0 halo & last-block tail
            val.x = (g     >= 0 && g     < n) ? noise[g]     : 0.0f;
            val.y = (g + 1 >= 0 && g + 1 < n) ? noise[g + 1] : 0.0f;
            val.z = (g + 2 >= 0 && g + 2 < n) ? noise[g + 2] : 0.0f;
            val.w = (g + 3 >= 0 && g + 3 < n) ? noise[g + 3] : 0.0f;
        }
        *(vfloat4*)(xs + i) = val;
    }
    __syncthreads();                // barrier 1

    // ---- transpose: own contiguous 20 samples -> registers (5x b128) ----
    const int l0 = tid * CHUNK;     // 80B-aligned -> 16B-aligned ds_read_b128
    vfloat4 xq[5];
    #pragma unroll
    for (int q = 0; q < 5; ++q)
        xq[q] = *(const vfloat4*)(xs + l0 + 4 * q);

    // ---- phase B: zero-state chain in registers; z in place ----
    float yv = 0.0f, zv = 0.0f;
    #pragma unroll
    for (int j = 0; j < CHUNK; ++j) {
        float x  = xq[j >> 2][j & 3];
        float yn = fmaf(a, yv, omc * x);
        zv = bb * (zv + (yn - yv));
        yv = yn;
        xq[j >> 2][j & 3] = zv;                 // own register slot
    }

    // ---- intra-wave Hillis-Steele scan (operator squaring) ----
    Op m1 = { a, bb * (a - 1.0f), bb };
    Op m2 = opmul(m1, m1), m4 = opmul(m2, m2), m8 = opmul(m4, m4), m16 = opmul(m8, m8);
    Op P  = opmul(m16, m4);         // M^20 = M^CHUNK
    Op O  = { 1.0f, 0.0f, 1.0f };   // M^(CHUNK*lane), built from pre-square P
    float cy = yv, cz = zv;
    #pragma unroll
    for (int k = 0; k < 6; ++k) {
        if ((lane >> k) & 1) O = opmul(P, O);
        int d = 1 << k;
        float py = __shfl_up(cy, d, 64);
        float pz = __shfl_up(cz, d, 64);
        if (lane >= d) {
            cy = fmaf(P.a, py, cy);
            cz = fmaf(P.w, py, fmaf(P.b, pz, cz));
        }
        P = opmul(P, P);            // after loop: P = M^1280 (wave operator)
    }
    if (lane == 63) { swy[wid] = cy; swz[wid] = cz; }

    // exclusive intra-wave zero-state value
    float ey = __shfl_up(cy, 1, 64);
    float ez = __shfl_up(cz, 1, 64);
    if (lane == 0) { ey = 0.0f; ez = 0.0f; }

    __syncthreads();                // barrier 2

    if (wid > 0) {                  // wave-uniform branch; wave 0 = halo only
        // cross-wave zero-init prefix: state entering this wave
        float pry = 0.0f, prz = 0.0f;
        for (int u = 0; u < wid; ++u) {         // wave-uniform trip count
            float ny = fmaf(P.a, pry, swy[u]);
            float nz = fmaf(P.w, pry, fmaf(P.b, prz, swz[u]));
            pry = ny; prz = nz;
        }
        // thread incoming state s_in = O * pref_wid + excl
        float yh = fmaf(O.a, pry, ey);
        float zh = ez + fmaf(O.w, pry, O.b * prz);

        // ---- phase D: homogeneous correction + envelope, in registers ----
        const float attack = fmaxf(params[0], 1e-7f);
        const float decay  = fmaxf(params[1], 1e-7f);
        const float gain   = fmaxf(params[4], 1e-7f);
        const float inv    = 1.0f / (float)(n - 1);
        const float ia = -1.0f / attack;
        const float id = -1.0f / decay;
        const float t0 = (float)(base + l0) * inv;  // >= 0 for all writers
        float ea = __expf(ia * t0);                 // exp(-t/attack)
        float ed = __expf(id * t0) * gain;          // exp(-t/decay) * gain
        const float ra = __expf(ia * inv);
        const float rd = __expf(id * inv);

        #pragma unroll
        for (int j = 0; j < CHUNK; ++j) {
            float yn = a * yh;                  // h_j = M h_{j-1}, h_{-1}=s_in
            zh = bb * (zh + (yn - yh));
            yh = yn;
            float zt = xq[j >> 2][j & 3] + zh;  // total = zero-state + homog
            xq[j >> 2][j & 3] = zt * ((1.0f - ea) * ed);
            ea *= ra; ed *= rd;
        }

        // ---- outputs back IN PLACE (own slots, 5x b128) ----
        #pragma unroll
        for (int q = 0; q < 5; ++q)
            *(vfloat4*)(xs + l0 + 4 * q) = xq[q];
    }
    __syncthreads();                // barrier 3

    // ---- coalesced nontemporal float4 store of [HALO, TWORDS) ----
    for (int v = tid; v < (SAMP >> 2); v += BLOCK) {
        int i = v << 2;
        int g = B + i;
        if (g + 4 <= n) {
            vfloat4 val = *(const vfloat4*)(xs + HALO + i);
            __builtin_nontemporal_store(val, (vfloat4*)(out + g));
        } else {
            for (int c = 0; c < 4; ++c)
                if (g + c < n) out[g + c] = xs[HALO + i + c];
        }
    }
}

extern "C" void kernel_launch(void* const* d_in, const int* in_sizes, int n_in,
                              void* d_out, int out_size, void* d_ws, size_t ws_size,
                              hipStream_t stream) {
    const float* params = (const float*)d_in[0];
    const float* noise  = (const float*)d_in[1];
    float* out = (float*)d_out;
    int n = in_sizes[1];
    int grid = (n + SAMP - 1) / SAMP;   // 1093 blocks @ n = 4194304
    ng_r8<<<grid, BLOCK, 0, stream>>>(params, noise, out, n);
}